// Round 1
// baseline (67.383 us; speedup 1.0000x reference)
//
#include <hip/hip_runtime.h>
#include <math.h>

// ChamferLoss: pc_src [B,3,M] f32, pc_dst [B,3,N] f32 -> scalar mean over (B,M)
// of min_n ||src_m - dst_n||.
//
// Identity: min_n d2 = |a|^2 + min_n (|b|^2 - 2 a.b).
// Precompute per-dst float4 (-2bx,-2by,-2bz,|b|^2) so the inner loop is
// 3 FMA + 1 min per (src,dst) pair. Pure VALU-f32 compute; inputs are L2-resident.

#define TPB 256

constexpr int NB = 4;
constexpr int NM = 8192;
constexpr int NN = 8192;
constexpr int NSEG = 16;                         // dst split for parallelism
constexpr int SEG = NN / NSEG;                   // 512 dst per segment
constexpr int SPT = 4;                           // src points per thread
constexpr int SRC_PER_BLOCK = TPB * SPT;         // 1024
constexpr int CHUNKS = (NB * NM) / SRC_PER_BLOCK;    // 32
constexpr int CHUNKS_PER_B = NM / SRC_PER_BLOCK;     // 8
constexpr int NBLK_C = (NB * NM) / TPB;          // 128

// Order-preserving float<->uint encode so unsigned atomicMin == float min.
__device__ __forceinline__ unsigned enc_f32(float f) {
    unsigned u = __float_as_uint(f);
    return (u & 0x80000000u) ? ~u : (u | 0x80000000u);
}
__device__ __forceinline__ float dec_f32(unsigned u) {
    unsigned b = (u & 0x80000000u) ? (u ^ 0x80000000u) : ~u;
    return __uint_as_float(b);
}

// Kernel A: build dst4 = (-2x,-2y,-2z, x^2+y^2+z^2) and init min array to +"inf".
__global__ __launch_bounds__(TPB) void prep_kernel(const float* __restrict__ dst,
                                                   float4* __restrict__ dst4,
                                                   unsigned* __restrict__ minenc) {
    int idx = blockIdx.x * TPB + threadIdx.x;
    if (idx < NB * NN) {
        int b = idx / NN, n = idx % NN;
        const float* p = dst + (size_t)b * 3 * NN;
        float x = p[n], y = p[NN + n], z = p[2 * NN + n];
        dst4[idx] = make_float4(-2.0f * x, -2.0f * y, -2.0f * z,
                                fmaf(x, x, fmaf(y, y, z * z)));
    }
    if (idx < NB * NM) minenc[idx] = 0xFFFFFFFFu;   // encodes > +inf
}

// Kernel B: per (src-chunk, dst-segment) block, running min of (b^2 - 2 a.b).
__global__ __launch_bounds__(TPB) void minseg_kernel(const float* __restrict__ src,
                                                     const float4* __restrict__ dst4,
                                                     unsigned* __restrict__ minenc) {
    int chunk = blockIdx.x / NSEG;
    int seg   = blockIdx.x % NSEG;
    int b  = chunk / CHUNKS_PER_B;
    int m0 = (chunk % CHUNKS_PER_B) * SRC_PER_BLOCK + threadIdx.x;
    const float* sp = src + (size_t)b * 3 * NM;

    float ax[SPT], ay[SPT], az[SPT], mn[SPT];
#pragma unroll
    for (int k = 0; k < SPT; ++k) {
        int m = m0 + k * TPB;
        ax[k] = sp[m];
        ay[k] = sp[NM + m];
        az[k] = sp[2 * NM + m];
        mn[k] = 3.4e38f;
    }

    const float4* dp = dst4 + b * NN + seg * SEG;
#pragma unroll 4
    for (int j = 0; j < SEG; ++j) {
        float4 d = dp[j];                 // uniform across block -> broadcast
#pragma unroll
        for (int k = 0; k < SPT; ++k) {
            float t = fmaf(az[k], d.z, d.w);
            t = fmaf(ay[k], d.y, t);
            t = fmaf(ax[k], d.x, t);
            mn[k] = fminf(mn[k], t);
        }
    }

#pragma unroll
    for (int k = 0; k < SPT; ++k) {
        int gm = b * NM + m0 + k * TPB;
        atomicMin(&minenc[gm], enc_f32(mn[k]));  // exact min: order-independent
    }
}

// Kernel C: per src point, d = sqrt(max(a^2 + minval, 0)); block tree-sum.
__global__ __launch_bounds__(TPB) void finish_kernel(const float* __restrict__ src,
                                                     const unsigned* __restrict__ minenc,
                                                     float* __restrict__ bsums) {
    int gm = blockIdx.x * TPB + threadIdx.x;
    int b = gm / NM, m = gm % NM;
    const float* sp = src + (size_t)b * 3 * NM;
    float x = sp[m], y = sp[NM + m], z = sp[2 * NM + m];
    float a2 = fmaf(x, x, fmaf(y, y, z * z));
    float v = dec_f32(minenc[gm]);
    float d = sqrtf(fmaxf(a2 + v, 0.0f));

    for (int off = 32; off > 0; off >>= 1) d += __shfl_down(d, off);
    __shared__ float wsum[4];
    int lane = threadIdx.x & 63, w = threadIdx.x >> 6;
    if (lane == 0) wsum[w] = d;
    __syncthreads();
    if (threadIdx.x == 0)
        bsums[blockIdx.x] = (wsum[0] + wsum[1]) + (wsum[2] + wsum[3]);
}

// Kernel D: deterministic final tree-sum of block sums, scale to mean.
__global__ __launch_bounds__(TPB) void final_kernel(const float* __restrict__ bsums,
                                                    float* __restrict__ out) {
    float v = (threadIdx.x < NBLK_C) ? bsums[threadIdx.x] : 0.0f;
    for (int off = 32; off > 0; off >>= 1) v += __shfl_down(v, off);
    __shared__ float wsum[4];
    int lane = threadIdx.x & 63, w = threadIdx.x >> 6;
    if (lane == 0) wsum[w] = v;
    __syncthreads();
    if (threadIdx.x == 0)
        out[0] = ((wsum[0] + wsum[1]) + (wsum[2] + wsum[3])) * (1.0f / (NB * NM));
}

extern "C" void kernel_launch(void* const* d_in, const int* in_sizes, int n_in,
                              void* d_out, int out_size, void* d_ws, size_t ws_size,
                              hipStream_t stream) {
    const float* src = (const float*)d_in[0];   // [B,3,M]
    const float* dst = (const float*)d_in[1];   // [B,3,N]
    float* out = (float*)d_out;

    char* ws = (char*)d_ws;
    float4*   dst4   = (float4*)ws;                                  // 512 KB
    unsigned* minenc = (unsigned*)(ws + (size_t)NB * NN * 16);       // 128 KB
    float*    bsums  = (float*)(ws + (size_t)NB * NN * 16
                                   + (size_t)NB * NM * 4);           // 512 B

    int nA = (NB * NN > NB * NM ? NB * NN : NB * NM);
    prep_kernel<<<(nA + TPB - 1) / TPB, TPB, 0, stream>>>(dst, dst4, minenc);
    minseg_kernel<<<CHUNKS * NSEG, TPB, 0, stream>>>(src, dst4, minenc);
    finish_kernel<<<NBLK_C, TPB, 0, stream>>>(src, minenc, bsums);
    final_kernel<<<1, TPB, 0, stream>>>(bsums, out);
}

// Round 2
// 46.785 us; speedup vs baseline: 1.4403x; 1.4403x over previous
//
#include <hip/hip_runtime.h>
#include <math.h>

// ChamferLoss: pc_src [B,3,M] f32, pc_dst [B,3,N] f32 -> scalar mean over (B,M)
// of min_n ||src_m - dst_n||.
//
// Identity: min_n d2 = |a|^2 + min_n (|b|^2 - 2 a.b).
// Per-dst float4 (-2bx,-2by,-2bz,|b|^2) -> inner loop is 3 FMA + part of a
// v_min3 per pair (3.5 VALU ops/pair). Pure VALU-f32; inputs L2-resident.
//
// R1 -> R2: occupancy 17%->max (NSEG 16->64, 2048 blocks = 8 waves/SIMD),
// atomics replaced by per-segment partial-min stores reduced in finish kernel,
// min3 fusion (2 dst/iter).

#define TPB 256

constexpr int NB = 4;
constexpr int NM = 8192;
constexpr int NN = 8192;
constexpr int NSEG = 64;                          // dst split for parallelism
constexpr int SEG = NN / NSEG;                    // 128 dst per segment
constexpr int SPT = 4;                            // src points per thread
constexpr int SRC_PER_BLOCK = TPB * SPT;          // 1024
constexpr int CHUNKS = (NB * NM) / SRC_PER_BLOCK; // 32
constexpr int CHUNKS_PER_B = NM / SRC_PER_BLOCK;  // 8
constexpr int NPTS = NB * NM;                     // 32768 src points
constexpr int NBLK_C = NPTS / TPB;                // 128

// Kernel A: build dst4 = (-2x,-2y,-2z, x^2+y^2+z^2).
__global__ __launch_bounds__(TPB) void prep_kernel(const float* __restrict__ dst,
                                                   float4* __restrict__ dst4) {
    int idx = blockIdx.x * TPB + threadIdx.x;
    int b = idx / NN, n = idx % NN;
    const float* p = dst + (size_t)b * 3 * NN;
    float x = p[n], y = p[NN + n], z = p[2 * NN + n];
    dst4[idx] = make_float4(-2.0f * x, -2.0f * y, -2.0f * z,
                            fmaf(x, x, fmaf(y, y, z * z)));
}

// Kernel B: per (src-chunk, dst-segment) block, running min of (b^2 - 2 a.b),
// stored as a per-segment partial (no atomics).
__global__ __launch_bounds__(TPB) void minseg_kernel(const float* __restrict__ src,
                                                     const float4* __restrict__ dst4,
                                                     float* __restrict__ part) {
    int chunk = blockIdx.x % CHUNKS;
    int seg   = blockIdx.x / CHUNKS;
    int b  = chunk / CHUNKS_PER_B;
    int m0 = (chunk % CHUNKS_PER_B) * SRC_PER_BLOCK + threadIdx.x;
    const float* sp = src + (size_t)b * 3 * NM;

    float ax[SPT], ay[SPT], az[SPT], mn[SPT];
#pragma unroll
    for (int k = 0; k < SPT; ++k) {
        int m = m0 + k * TPB;
        ax[k] = sp[m];
        ay[k] = sp[NM + m];
        az[k] = sp[2 * NM + m];
        mn[k] = 3.4e38f;
    }

    const float4* dp = dst4 + b * NN + seg * SEG;
#pragma unroll 4
    for (int j = 0; j < SEG; j += 2) {
        float4 d0 = dp[j];                // uniform -> scalar loads
        float4 d1 = dp[j + 1];
#pragma unroll
        for (int k = 0; k < SPT; ++k) {
            float t0 = fmaf(az[k], d0.z, d0.w);
            t0 = fmaf(ay[k], d0.y, t0);
            t0 = fmaf(ax[k], d0.x, t0);
            float t1 = fmaf(az[k], d1.z, d1.w);
            t1 = fmaf(ay[k], d1.y, t1);
            t1 = fmaf(ax[k], d1.x, t1);
            mn[k] = fminf(fminf(mn[k], t0), t1);   // -> v_min3_f32
        }
    }

#pragma unroll
    for (int k = 0; k < SPT; ++k) {
        int gm = b * NM + m0 + k * TPB;
        part[(size_t)seg * NPTS + gm] = mn[k];     // coalesced store
    }
}

// Kernel C: per src point, min over segments, d = sqrt(max(a^2 + v, 0)),
// block tree-sum (deterministic).
__global__ __launch_bounds__(TPB) void finish_kernel(const float* __restrict__ src,
                                                     const float* __restrict__ part,
                                                     float* __restrict__ bsums) {
    int gm = blockIdx.x * TPB + threadIdx.x;
    int b = gm / NM, m = gm % NM;

    float v = part[gm];
#pragma unroll 8
    for (int s = 1; s < NSEG; s += 2)
        v = fminf(fminf(v, part[(size_t)s * NPTS + gm]),
                  part[(size_t)(s + 1 < NSEG ? s + 1 : s) * NPTS + gm]);

    const float* sp = src + (size_t)b * 3 * NM;
    float x = sp[m], y = sp[NM + m], z = sp[2 * NM + m];
    float a2 = fmaf(x, x, fmaf(y, y, z * z));
    float d = sqrtf(fmaxf(a2 + v, 0.0f));

    for (int off = 32; off > 0; off >>= 1) d += __shfl_down(d, off);
    __shared__ float wsum[4];
    int lane = threadIdx.x & 63, w = threadIdx.x >> 6;
    if (lane == 0) wsum[w] = d;
    __syncthreads();
    if (threadIdx.x == 0)
        bsums[blockIdx.x] = (wsum[0] + wsum[1]) + (wsum[2] + wsum[3]);
}

// Kernel D: deterministic final tree-sum of block sums, scale to mean.
__global__ __launch_bounds__(TPB) void final_kernel(const float* __restrict__ bsums,
                                                    float* __restrict__ out) {
    float v = (threadIdx.x < NBLK_C) ? bsums[threadIdx.x] : 0.0f;
    for (int off = 32; off > 0; off >>= 1) v += __shfl_down(v, off);
    __shared__ float wsum[4];
    int lane = threadIdx.x & 63, w = threadIdx.x >> 6;
    if (lane == 0) wsum[w] = v;
    __syncthreads();
    if (threadIdx.x == 0)
        out[0] = ((wsum[0] + wsum[1]) + (wsum[2] + wsum[3])) * (1.0f / NPTS);
}

extern "C" void kernel_launch(void* const* d_in, const int* in_sizes, int n_in,
                              void* d_out, int out_size, void* d_ws, size_t ws_size,
                              hipStream_t stream) {
    const float* src = (const float*)d_in[0];   // [B,3,M]
    const float* dst = (const float*)d_in[1];   // [B,3,N]
    float* out = (float*)d_out;

    char* ws = (char*)d_ws;
    float4* dst4 = (float4*)ws;                                   // 512 KB
    float*  part = (float*)(ws + (size_t)NB * NN * 16);           // 8 MB
    float*  bsums = (float*)(ws + (size_t)NB * NN * 16
                                + (size_t)NSEG * NPTS * 4);       // 512 B

    prep_kernel<<<(NB * NN) / TPB, TPB, 0, stream>>>(dst, dst4);
    minseg_kernel<<<CHUNKS * NSEG, TPB, 0, stream>>>(src, dst4, part);
    finish_kernel<<<NBLK_C, TPB, 0, stream>>>(src, part, bsums);
    final_kernel<<<1, TPB, 0, stream>>>(bsums, out);
}

// Round 3
// 34.115 us; speedup vs baseline: 1.9752x; 1.3714x over previous
//
#include <hip/hip_runtime.h>
#include <math.h>

// ChamferLoss: pc_src [B,3,M] f32, pc_dst [B,3,N] f32 -> scalar mean over (B,M)
// of min_n ||src_m - dst_n||.
//
// Identity: min_n d2 = |a|^2 + min_n (|b|^2 - 2 a.b).
// Per-dst float4 (-2bx,-2by,-2bz,|b|^2) staged in LDS -> inner loop is
// 3 FMA + half a v_min3 per pair (3.5 VALU lane-ops/pair, floor ~11.9 us).
//
// R2 -> R3: SPT 4->8 (2x ILP, half the loads/FLOP), dst4 built per-block in
// LDS (prep kernel dropped, broadcast ds_read), partial-min tensor replaced by
// order-encoded atomicMin into a 128 KB array (exact + deterministic), init
// via hipMemsetAsync(0xFF).

#define TPB 256

constexpr int NB = 4;
constexpr int NM = 8192;
constexpr int NN = 8192;
constexpr int NSEG = 64;                          // dst segments
constexpr int SEG = NN / NSEG;                    // 128 dst per segment
constexpr int SPT = 8;                            // src points per thread
constexpr int SRC_PER_BLOCK = TPB * SPT;          // 2048
constexpr int NPTS = NB * NM;                     // 32768
constexpr int CHUNKS = NPTS / SRC_PER_BLOCK;      // 16
constexpr int CHUNKS_PER_B = NM / SRC_PER_BLOCK;  // 4
constexpr int NBLK_C = NPTS / TPB;                // 128

// Order-preserving float<->uint encode so unsigned atomicMin == float min.
__device__ __forceinline__ unsigned enc_f32(float f) {
    unsigned u = __float_as_uint(f);
    return (u & 0x80000000u) ? ~u : (u | 0x80000000u);
}
__device__ __forceinline__ float dec_f32(unsigned u) {
    unsigned b = (u & 0x80000000u) ? (u ^ 0x80000000u) : ~u;
    return __uint_as_float(b);
}

// Kernel B: per (src-chunk, dst-segment) block. Build the segment's dst4 in
// LDS, then running min of (b^2 - 2 a.b) over 8 src points per thread.
__global__ __launch_bounds__(TPB, 4) void minseg_kernel(const float* __restrict__ src,
                                                        const float* __restrict__ dst,
                                                        unsigned* __restrict__ minenc) {
    __shared__ float4 sdst[SEG];                  // 2 KB

    int chunk = blockIdx.x % CHUNKS;
    int seg   = blockIdx.x / CHUNKS;
    int b  = chunk / CHUNKS_PER_B;
    int t  = threadIdx.x;

    if (t < SEG) {
        int n = seg * SEG + t;
        const float* p = dst + (size_t)b * 3 * NN;
        float x = p[n], y = p[NN + n], z = p[2 * NN + n];
        sdst[t] = make_float4(-2.0f * x, -2.0f * y, -2.0f * z,
                              fmaf(x, x, fmaf(y, y, z * z)));
    }

    int m0 = (chunk % CHUNKS_PER_B) * SRC_PER_BLOCK + t;
    const float* sp = src + (size_t)b * 3 * NM;

    float ax[SPT], ay[SPT], az[SPT], mn[SPT];
#pragma unroll
    for (int k = 0; k < SPT; ++k) {
        int m = m0 + k * TPB;
        ax[k] = sp[m];
        ay[k] = sp[NM + m];
        az[k] = sp[2 * NM + m];
        mn[k] = 3.4e38f;
    }
    __syncthreads();

#pragma unroll 4
    for (int j = 0; j < SEG; j += 2) {
        float4 d0 = sdst[j];                      // uniform -> LDS broadcast
        float4 d1 = sdst[j + 1];
#pragma unroll
        for (int k = 0; k < SPT; ++k) {
            float t0 = fmaf(az[k], d0.z, d0.w);
            t0 = fmaf(ay[k], d0.y, t0);
            t0 = fmaf(ax[k], d0.x, t0);
            float t1 = fmaf(az[k], d1.z, d1.w);
            t1 = fmaf(ay[k], d1.y, t1);
            t1 = fmaf(ax[k], d1.x, t1);
            mn[k] = fminf(fminf(mn[k], t0), t1);  // -> v_min3_f32
        }
    }

#pragma unroll
    for (int k = 0; k < SPT; ++k) {
        int gm = b * NM + m0 + k * TPB;
        atomicMin(&minenc[gm], enc_f32(mn[k]));   // exact, order-independent
    }
}

// Kernel C: per src point, d = sqrt(max(a^2 + minval, 0)); block tree-sum.
__global__ __launch_bounds__(TPB) void finish_kernel(const float* __restrict__ src,
                                                     const unsigned* __restrict__ minenc,
                                                     float* __restrict__ bsums) {
    int gm = blockIdx.x * TPB + threadIdx.x;
    int b = gm / NM, m = gm % NM;
    const float* sp = src + (size_t)b * 3 * NM;
    float x = sp[m], y = sp[NM + m], z = sp[2 * NM + m];
    float a2 = fmaf(x, x, fmaf(y, y, z * z));
    float v = dec_f32(minenc[gm]);
    float d = sqrtf(fmaxf(a2 + v, 0.0f));

    for (int off = 32; off > 0; off >>= 1) d += __shfl_down(d, off);
    __shared__ float wsum[4];
    int lane = threadIdx.x & 63, w = threadIdx.x >> 6;
    if (lane == 0) wsum[w] = d;
    __syncthreads();
    if (threadIdx.x == 0)
        bsums[blockIdx.x] = (wsum[0] + wsum[1]) + (wsum[2] + wsum[3]);
}

// Kernel D: deterministic final tree-sum of block sums, scale to mean.
__global__ __launch_bounds__(TPB) void final_kernel(const float* __restrict__ bsums,
                                                    float* __restrict__ out) {
    float v = (threadIdx.x < NBLK_C) ? bsums[threadIdx.x] : 0.0f;
    for (int off = 32; off > 0; off >>= 1) v += __shfl_down(v, off);
    __shared__ float wsum[4];
    int lane = threadIdx.x & 63, w = threadIdx.x >> 6;
    if (lane == 0) wsum[w] = v;
    __syncthreads();
    if (threadIdx.x == 0)
        out[0] = ((wsum[0] + wsum[1]) + (wsum[2] + wsum[3])) * (1.0f / NPTS);
}

extern "C" void kernel_launch(void* const* d_in, const int* in_sizes, int n_in,
                              void* d_out, int out_size, void* d_ws, size_t ws_size,
                              hipStream_t stream) {
    const float* src = (const float*)d_in[0];   // [B,3,M]
    const float* dst = (const float*)d_in[1];   // [B,3,N]
    float* out = (float*)d_out;

    char* ws = (char*)d_ws;
    unsigned* minenc = (unsigned*)ws;                       // 128 KB
    float*    bsums  = (float*)(ws + (size_t)NPTS * 4);     // 512 B

    hipMemsetAsync(minenc, 0xFF, (size_t)NPTS * 4, stream); // encodes > +inf
    minseg_kernel<<<CHUNKS * NSEG, TPB, 0, stream>>>(src, dst, minenc);
    finish_kernel<<<NBLK_C, TPB, 0, stream>>>(src, minenc, bsums);
    final_kernel<<<1, TPB, 0, stream>>>(bsums, out);
}